// Round 2
// baseline (9777.349 us; speedup 1.0000x reference)
//
#include <hip/hip_runtime.h>
#include <math.h>

#define STEPS 19
#define NEG_SLOPE 0.01f
#define THREADS 256

__device__ __forceinline__ float lrelu(float x) {
    // slope < 1  =>  lrelu(x) == max(x, 0.01x)  (2 VALU ops: v_mul + v_max)
    return fmaxf(x, NEG_SLOPE * x);
}

__device__ __forceinline__ float sigm(float x) {
    // 1/(1+exp(-x)): v_exp_f32 + v_rcp_f32, ~1-2 ulp, far inside 1e-2 threshold
    return __builtin_amdgcn_rcpf(1.0f + __expf(-x));
}

__global__ __launch_bounds__(THREADS) void recurrent_kernel(
    const float* __restrict__ w,
    const float* __restrict__ Wh1, const float* __restrict__ bh1,
    const float* __restrict__ Wh2, const float* __restrict__ bh2,
    const float* __restrict__ Wh3, const float* __restrict__ bh3,
    const float* __restrict__ Wz1, const float* __restrict__ bz1,
    const float* __restrict__ Wz2, const float* __restrict__ bz2,
    const float* __restrict__ Wz3, const float* __restrict__ bz3,
    float* __restrict__ out, int nrows)
{
    // Layer-1 weights packed {W[0][k], W[1][k], b[k], pad} -> one ds_read_b128/k.
    __shared__ float4 sH1[50];
    __shared__ float4 sZ1[50];
    __shared__ float  sWh2[1000]; __shared__ float sbh2[20];
    __shared__ float  sWz2[1000]; __shared__ float sbz2[20];
    __shared__ float2 sWh3[20];   __shared__ float2 sWz3[20];
    __shared__ float2 sbh3v;      __shared__ float2 sbz3v;

    const int t = threadIdx.x;
    if (t < 50) {
        sH1[t] = make_float4(Wh1[t], Wh1[50 + t], bh1[t], 0.0f);
        sZ1[t] = make_float4(Wz1[t], Wz1[50 + t], bz1[t], 0.0f);
    }
    for (int i = t; i < 1000; i += THREADS) {
        sWh2[i] = Wh2[i];
        sWz2[i] = Wz2[i];
    }
    if (t < 20) {
        sbh2[t] = bh2[t];
        sbz2[t] = bz2[t];
        sWh3[t] = make_float2(Wh3[2 * t], Wh3[2 * t + 1]);
        sWz3[t] = make_float2(Wz3[2 * t], Wz3[2 * t + 1]);
    }
    if (t == 0) {
        sbh3v = make_float2(bh3[0], bh3[1]);
        sbz3v = make_float2(bz3[0], bz3[1]);
    }
    __syncthreads();

    const int row = blockIdx.x * THREADS + t;
    if (row >= nrows) return;

    const float2 w2 = *(const float2*)(w + 2 * (size_t)row);
    float h0 = w2.x, h1 = w2.y;

    float* __restrict__ orow = out + (size_t)row * (STEPS * 2);

    for (int s = 0; s < STEPS; ++s) {
        // ---- h path: fused layer1->layer2 (no [50] array materialized) ----
        float a2[20];
        #pragma unroll
        for (int i = 0; i < 20; ++i) a2[i] = sbh2[i];
        #pragma unroll
        for (int k = 0; k < 50; ++k) {
            const float4 wk = sH1[k];
            const float a = lrelu(fmaf(h1, wk.y, fmaf(h0, wk.x, wk.z)));
            #pragma unroll
            for (int i = 0; i < 20; ++i) a2[i] = fmaf(a, sWh2[k * 20 + i], a2[i]);
        }
        // layer h3: [20] -> [2]
        float nh0 = sbh3v.x, nh1 = sbh3v.y;
        #pragma unroll
        for (int i = 0; i < 20; ++i) {
            const float a = lrelu(a2[i]);
            const float2 w3 = sWh3[i];
            nh0 = fmaf(a, w3.x, nh0);
            nh1 = fmaf(a, w3.y, nh1);
        }
        h0 = lrelu(nh0);
        h1 = lrelu(nh1);

        // ---- z path (uses the NEW h): fused layer1->layer2 ----
        float z2[20];
        #pragma unroll
        for (int i = 0; i < 20; ++i) z2[i] = sbz2[i];
        #pragma unroll
        for (int k = 0; k < 50; ++k) {
            const float4 wk = sZ1[k];
            const float zk = sigm(fmaf(h1, wk.y, fmaf(h0, wk.x, wk.z)));
            #pragma unroll
            for (int i = 0; i < 20; ++i) z2[i] = fmaf(zk, sWz2[k * 20 + i], z2[i]);
        }
        float zo0 = sbz3v.x, zo1 = sbz3v.y;
        #pragma unroll
        for (int i = 0; i < 20; ++i) {
            const float zz = sigm(z2[i]);
            const float2 w3 = sWz3[i];
            zo0 = fmaf(zz, w3.x, zo0);
            zo1 = fmaf(zz, w3.y, zo1);
        }
        zo0 = sigm(zo0);
        zo1 = sigm(zo1);

        float2 o; o.x = zo0; o.y = zo1;
        *(float2*)(orow + 2 * s) = o;
    }
}

extern "C" void kernel_launch(void* const* d_in, const int* in_sizes, int n_in,
                              void* d_out, int out_size, void* d_ws, size_t ws_size,
                              hipStream_t stream) {
    const float* w   = (const float*)d_in[0];
    const float* Wh1 = (const float*)d_in[1];
    const float* bh1 = (const float*)d_in[2];
    const float* Wh2 = (const float*)d_in[3];
    const float* bh2 = (const float*)d_in[4];
    const float* Wh3 = (const float*)d_in[5];
    const float* bh3 = (const float*)d_in[6];
    const float* Wz1 = (const float*)d_in[7];
    const float* bz1 = (const float*)d_in[8];
    const float* Wz2 = (const float*)d_in[9];
    const float* bz2 = (const float*)d_in[10];
    const float* Wz3 = (const float*)d_in[11];
    const float* bz3 = (const float*)d_in[12];
    float* out = (float*)d_out;

    const int nrows = in_sizes[0] / 2;  // w is [B,2]
    const int blocks = (nrows + THREADS - 1) / THREADS;

    recurrent_kernel<<<blocks, THREADS, 0, stream>>>(
        w, Wh1, bh1, Wh2, bh2, Wh3, bh3,
        Wz1, bz1, Wz2, bz2, Wz3, bz3, out, nrows);
}